// Round 14
// baseline (42.210 us; speedup 1.0000x reference)
//
#include <hip/hip_runtime.h>
#include <hip/hip_bf16.h>
#include <stdint.h>

typedef __attribute__((ext_vector_type(8))) short bf16x8;
typedef __attribute__((ext_vector_type(4))) float f32x4;
typedef __attribute__((ext_vector_type(16))) float f32x16;

#define MFMA32(a, b, c) __builtin_amdgcn_mfma_f32_32x32x16_bf16((a), (b), (c), 0, 0, 0)

__device__ __forceinline__ unsigned short f2bf_rn(float f) {
    union { __bf16 b; unsigned short u; } v;
    v.b = (__bf16)f;
    return v.u;
}

// pack 2 floats -> 2 bf16 in a uint (compiler fuses to v_cvt_pk_bf16_f32)
__device__ __forceinline__ unsigned int pk2(float lo, float hi) {
    union { unsigned short s[2]; unsigned int u; } r;
    r.s[0] = f2bf_rn(lo); r.s[1] = f2bf_rn(hi);
    return r.u;
}

__device__ __forceinline__ void gload_lds16(const void* g, void* l) {
    __builtin_amdgcn_global_load_lds(
        (const __attribute__((address_space(1))) void*)g,
        (__attribute__((address_space(3))) void*)l, 16, 0, 0);
}

// ---------------------------------------------------------------------------
// prep_h: transpose each 128x128 fp32 block of the 8 H tensors to bf16.
//   ht[j][blk][k][r] = h_j[blk][r][k]
// 256 WGs = jblk(64) x k-quarter(4).
// ---------------------------------------------------------------------------
__global__ __launch_bounds__(256) void prep_h(
    const float* __restrict__ h0, const float* __restrict__ h1,
    const float* __restrict__ h2, const float* __restrict__ h3,
    const float* __restrict__ h4, const float* __restrict__ h5,
    const float* __restrict__ h6, const float* __restrict__ h7,
    unsigned short* __restrict__ ht)
{
    const float* hmap[8] = {h0, h1, h2, h3, h4, h5, h6, h7};
    const int wg = blockIdx.x;            // 256 = jblk(64) x quarter(4)
    const int jblk = wg >> 2, qt = wg & 3;
    const float* src = hmap[jblk >> 3] + (jblk & 7) * 16384;
    unsigned short* dst = ht + jblk * 16384;
    __shared__ unsigned short tile[32 * 129];
    const int t = threadIdx.x;
    #pragma unroll
    for (int i = 0; i < 16; ++i) {
        int idx = t + 256 * i;            // 4096 = r(128) x kk(32)
        int r = idx >> 5, kk = idx & 31;
        tile[kk * 129 + r] = f2bf_rn(src[r * 128 + qt * 32 + kk]);
    }
    __syncthreads();
    #pragma unroll
    for (int i = 0; i < 16; ++i) {
        int idx = t + 256 * i;            // 4096 = k(32) x r(128)
        int k = idx >> 7, r = idx & 127;
        dst[(qt * 32 + k) * 128 + r] = tile[k * 129 + r];
    }
}

// ---------------------------------------------------------------------------
// bilin_main: 256 WGs = (b,p,q), q = bid&7 (XCD-locked). 256 threads =
// 4 waves, wave wn owns output cols wn*32..+32, full K=128. 32x32x16 MFMA.
// R14: PAIRED PHASES — 4 phases of (c_re, c_im) sharing one X plane:
//   P0=(c0,c6) P1=(c1,c7) on Xre; P2=(c2,c4) P3=(c3,c5) on Xim.
//   Phase: A(re) | MID | [issue wre(ph+1) (+P0: xim restage)] B(re) A(im)
//          B(im) | END | [issue wim/lre/lim(ph+1)] (+P1: reload xf from im).
//   B(re)||A(im) and B(re)||B(im) are independent chains (different y
//   accumulators) in one scheduling region -> latency overlap at
//   1 wave/SIMD without cross-barrier accumulator arrays (R12 lesson).
//   Barriers: 17 (R13) -> 9.
// Xim path (no stall): prologue converts BOTH planes from one fp32 read;
// re -> LDS, im -> global workspace (pre-swizzled layout).  Restaged into
// the (dead after prologue load_xf) xplane via gload_lds during P0; xf
// switched after END(P1).  No fp32 re-read.
// LDS = X 32K | wre 32K | wim 32K | lre 32K | lim 32K = 160 KB exact; all
// single-buffered, every stage issue >= 1 full compute block before its
// draining barrier.  Regs: y 128 + xf 128 + u 64 (reused re/im) + wfr/lfr
// transients ~= 390 peak (< 450 no-spill, 1 wave/SIMD budget 512).
// LDS swizzle: 16B chunk ch of row at LDS[row][ch] = G[row][ch ^ (row&15)].
// ---------------------------------------------------------------------------
__global__ __launch_bounds__(256, 1) void bilin_main(
    const float* __restrict__ x, const int* __restrict__ perm,
    const unsigned short* __restrict__ ht,
    unsigned short* __restrict__ ximws,
    float* __restrict__ out)
{
    const int wg = blockIdx.x;
    const int q = wg & 7, p = (wg >> 3) & 7, b = wg >> 6;
    const int tid = threadIdx.x;
    const int lane = tid & 63, wn = tid >> 6;      // 4 waves
    const int l31 = lane & 31, hl = lane >> 5;

    __shared__ __align__(16) unsigned short smem[81920];   // 160 KB
    unsigned short* xplane = smem;                         // 32 KB
    unsigned short* wre = smem + 16384;
    unsigned short* wim = smem + 32768;
    unsigned short* lre = smem + 49152;
    unsigned short* lim = smem + 65536;

    // phase tables: re-target c, im-target c; W tensor index = rperm[c]
    constexpr int pre_[4]  = {0, 1, 2, 3};
    constexpr int pim_[4]  = {6, 7, 4, 5};
    constexpr int rperm[8] = {0, 1, 3, 2, 4, 5, 7, 6};

    // ---- staging helpers (gload_lds: wave-uniform LDS base + lane*16) ----
    const int wubase = tid & ~63;
    auto stage_h = [&](unsigned short* dst, int blk) {
        const unsigned short* src = ht + blk * 16384;
        #pragma unroll
        for (int r = 0; r < 8; ++r) {
            const int idx = r * 256 + tid;          // 16B chunk 0..2047
            const int row = idx >> 4, cin = idx & 15;
            gload_lds16(src + row * 128 + ((cin ^ (row & 15)) << 3),
                        dst + ((r * 256 + wubase) << 3));
        }
    };

    // swizzled LDS fragment read: row in [0,128), chunk in [0,16)
    auto ldr = [&](const unsigned short* base, int row, int ch) -> bf16x8 {
        return *(const bf16x8*)(base + row * 128 + ((ch ^ (row & 15)) << 3));
    };

    unsigned short* myxim = ximws + (size_t)wg * 16384;

    // fused prep_x: one fp32 read -> re plane to LDS, im plane (pre-swizzled
    // layout) to the global workspace for later zero-cost gload restage.
    auto stage_x_both = [&]() {
        #pragma unroll
        for (int i = 0; i < 8; ++i) {
            const int idx = i * 256 + tid;
            const int row = idx >> 4, cin = idx & 15;
            const int n1 = perm[2 * p + (row >> 6)];
            const int n2 = perm[2 * q + (cin >> 3)];
            const int r1 = row & 63, r2 = (cin & 7) * 8;
            const float* sp = x + ((size_t)((b * 16 + n1) * 64 + r1) * 1024
                                   + n2 * 64 + r2) * 2;
            float4 v0 = *(const float4*)(sp);
            float4 v1 = *(const float4*)(sp + 4);
            float4 v2 = *(const float4*)(sp + 8);
            float4 v3 = *(const float4*)(sp + 12);
            bf16x8 re, im;
            re[0] = (short)f2bf_rn(v0.x); re[1] = (short)f2bf_rn(v0.z);
            re[2] = (short)f2bf_rn(v1.x); re[3] = (short)f2bf_rn(v1.z);
            re[4] = (short)f2bf_rn(v2.x); re[5] = (short)f2bf_rn(v2.z);
            re[6] = (short)f2bf_rn(v3.x); re[7] = (short)f2bf_rn(v3.z);
            im[0] = (short)f2bf_rn(v0.y); im[1] = (short)f2bf_rn(v0.w);
            im[2] = (short)f2bf_rn(v1.y); im[3] = (short)f2bf_rn(v1.w);
            im[4] = (short)f2bf_rn(v2.y); im[5] = (short)f2bf_rn(v2.w);
            im[6] = (short)f2bf_rn(v3.y); im[7] = (short)f2bf_rn(v3.w);
            const int woff = row * 128 + ((cin ^ (row & 15)) << 3);
            *(bf16x8*)(xplane + woff) = re;
            *(bf16x8*)(myxim + woff) = im;
        }
    };

    // restage xim workspace -> xplane (linear gloads; layout pre-swizzled)
    auto restage_xim = [&]() {
        #pragma unroll
        for (int r = 0; r < 8; ++r) {
            const int idx = r * 256 + tid;
            gload_lds16(myxim + ((size_t)idx << 3),
                        xplane + ((r * 256 + wubase) << 3));
        }
    };

    // X fragments for the whole 128-row tile, in registers (128 VGPRs)
    bf16x8 xf[4][8];
    auto load_xf = [&]() {
        #pragma unroll
        for (int m2 = 0; m2 < 4; ++m2)
            #pragma unroll
            for (int ks = 0; ks < 8; ++ks)
                xf[m2][ks] = ldr(xplane, m2 * 32 + l31, 2 * ks + hl);
    };

    // stage A: u = X . W_c (full K=128), wfr batched (R13-verified)
    auto do_A = [&](const unsigned short* wb, f32x16 (&u)[4]) {
        bf16x8 wfr[8];
        #pragma unroll
        for (int ks = 0; ks < 8; ++ks)
            wfr[ks] = ldr(wb, wn * 32 + l31, 2 * ks + hl);
        #pragma unroll
        for (int m2 = 0; m2 < 4; ++m2)
            #pragma unroll
            for (int e = 0; e < 16; ++e) u[m2][e] = 0.f;
        #pragma unroll
        for (int ks = 0; ks < 8; ++ks)
            #pragma unroll
            for (int m2 = 0; m2 < 4; ++m2)
                u[m2] = MFMA32(xf[m2][ks], wfr[ks], u[m2]);
    };

    // stage B: y += Lt_c . U — batched B-frags + lfr ping-pong (R13-verified)
    auto do_B = [&](const f32x16 (&u)[4], const unsigned short* lb,
                    f32x16 (&y)[4]) {
        union UF { unsigned int d[4]; bf16x8 v; };
        UF ufu[8];
        #pragma unroll
        for (int t = 0; t < 8; ++t) {
            const int f = t >> 1, qa = (t & 1) * 2, qb = qa + 1;
            unsigned int lo0 = pk2(u[f][4 * qa + 0], u[f][4 * qa + 1]);
            unsigned int lo1 = pk2(u[f][4 * qa + 2], u[f][4 * qa + 3]);
            unsigned int hi0 = pk2(u[f][4 * qb + 0], u[f][4 * qb + 1]);
            unsigned int hi1 = pk2(u[f][4 * qb + 2], u[f][4 * qb + 3]);
            unsigned int send0 = hl ? lo0 : hi0;
            unsigned int send1 = hl ? lo1 : hi1;
            unsigned int sx0 = (unsigned int)__shfl_xor((int)send0, 32);
            unsigned int sx1 = (unsigned int)__shfl_xor((int)send1, 32);
            ufu[t].d[0] = hl ? sx0 : lo0;
            ufu[t].d[1] = hl ? sx1 : lo1;
            ufu[t].d[2] = hl ? hi0 : sx0;
            ufu[t].d[3] = hl ? hi1 : sx1;
        }
        bf16x8 lcur[4], lnxt[4];
        #pragma unroll
        for (int mt = 0; mt < 4; ++mt)
            lcur[mt] = ldr(lb, mt * 32 + l31, hl);            // t=0
        #pragma unroll
        for (int t = 0; t < 8; ++t) {
            if (t < 7) {
                #pragma unroll
                for (int mt = 0; mt < 4; ++mt)
                    lnxt[mt] = ldr(lb, mt * 32 + l31, 2 * (t + 1) + hl);
            }
            #pragma unroll
            for (int mt = 0; mt < 4; ++mt)
                y[mt] = MFMA32(lcur[mt], ufu[t].v, y[mt]);
            #pragma unroll
            for (int mt = 0; mt < 4; ++mt) lcur[mt] = lnxt[mt];
        }
    };

    // ---- prologue: stage all 4 H tiles of P0 + X (re->LDS, im->ws) ----
    stage_h(wre, rperm[pre_[0]] * 8 + q);
    stage_h(wim, rperm[pim_[0]] * 8 + q);
    stage_h(lre, pre_[0] * 8 + p);
    stage_h(lim, pim_[0] * 8 + p);
    stage_x_both();
    __syncthreads();       // drains gloads; im stores drained (vmcnt) too
    load_xf();             // xf = Xre; xplane now dead until restage

    f32x16 yre[4], yim[4], u[4];
    #pragma unroll
    for (int i = 0; i < 4; ++i)
        #pragma unroll
        for (int e = 0; e < 16; ++e) { yre[i][e] = 0.f; yim[i][e] = 0.f; }

    #pragma unroll
    for (int ph = 0; ph < 4; ++ph) {
        // ---- A(re)
        do_A(wre, u);

        __syncthreads();   // MID: drains lre/lim(ph) (+wim(ph)), staged at
                           // END(ph-1) / prologue
        if (ph < 3)
            stage_h(wre, rperm[pre_[ph + 1]] * 8 + q);  // read pre-MID; drains END
        if (ph == 0)
            restage_xim();  // xplane dead since prologue; drains by END(P0)

        // ---- B(re) || A(im) || B(im): independent chains, one region
        do_B(u, lre, yre);
        do_A(wim, u);
        do_B(u, lim, yim);

        __syncthreads();   // END: drains wre(ph+1) + P0 restage; orders all
                           // single-buffer reuse
        if (ph < 3) {
            stage_h(wim, rperm[pim_[ph + 1]] * 8 + q);  // drain at MID(ph+1)
            stage_h(lre, pre_[ph + 1] * 8 + p);
            stage_h(lim, pim_[ph + 1] * 8 + p);
        }
        if (ph == 1)
            load_xf();      // xf = Xim (restaged during P0, drained END(P0))
    }

    // ---- epilogue: direct interleaved (re,im) stores, no reduction ----
    float2* o2 = (float2*)out;
    #pragma unroll
    for (int mt = 0; mt < 4; ++mt)
        #pragma unroll
        for (int j = 0; j < 16; ++j) {
            const int row = mt * 32 + (j & 3) + 8 * (j >> 2) + 4 * hl;
            float2 v;
            v.x = yre[mt][j];
            v.y = yim[mt][j];
            o2[(size_t)(b * 1024 + p * 128 + row) * 1024
               + q * 128 + wn * 32 + l31] = v;
        }
}

extern "C" void kernel_launch(void* const* d_in, const int* in_sizes, int n_in,
                              void* d_out, int out_size, void* d_ws, size_t ws_size,
                              hipStream_t stream) {
    const float* x  = (const float*)d_in[0];
    const int* perm = (const int*)d_in[1];
    unsigned short* ws = (unsigned short*)d_ws;
    // workspace (ushort units): ht 1M (2 MB) | ximws 4M (8 MB)
    unsigned short* htp   = ws;
    unsigned short* ximws = ws + 1024u * 1024u;

    hipLaunchKernelGGL(prep_h, dim3(256), dim3(256), 0, stream,
        (const float*)d_in[2], (const float*)d_in[3], (const float*)d_in[4],
        (const float*)d_in[5], (const float*)d_in[6], (const float*)d_in[7],
        (const float*)d_in[8], (const float*)d_in[9], htp);
    hipLaunchKernelGGL(bilin_main, dim3(256), dim3(256), 0, stream,
        x, perm, htp, ximws, (float*)d_out);
}